// Round 22
// baseline (166.860 us; speedup 1.0000x reference)
//
#include <hip/hip_runtime.h>

typedef short bf16x8 __attribute__((ext_vector_type(8)));
typedef float f32x4 __attribute__((ext_vector_type(4)));
typedef float f32x16 __attribute__((ext_vector_type(16)));
typedef unsigned short u16;
typedef unsigned short u16x8 __attribute__((ext_vector_type(8)));
typedef unsigned int u32;
typedef unsigned int u32x2 __attribute__((ext_vector_type(2)));
typedef unsigned int u32x4 __attribute__((ext_vector_type(4)));

#define MFMA16(a, b, c) __builtin_amdgcn_mfma_f32_16x16x32_bf16((a), (b), (c), 0, 0, 0)
#define MFMA32(a, b, c) __builtin_amdgcn_mfma_f32_32x32x16_bf16((a), (b), (c), 0, 0, 0)

__device__ __forceinline__ u16 f2bf(float f) {
  unsigned u = __builtin_bit_cast(unsigned, f);
  return (u16)((u + 0x7fffu + ((u >> 16) & 1u)) >> 16);
}

__device__ __forceinline__ unsigned cvt_pk_bf16(float lo, float hi) {
  unsigned r;
  asm("v_cvt_pk_bf16_f32 %0, %1, %2" : "=v"(r) : "v"(lo), "v"(hi));
  return r;
}

__device__ __forceinline__ void gload_lds16(const u16* g, u16* lds) {
  __builtin_amdgcn_global_load_lds((__attribute__((address_space(1))) void*)g,
                                   (__attribute__((address_space(3))) void*)lds,
                                   16, 0, 0);
}

// Publish LDS writes + block barrier WITHOUT draining vmcnt.
__device__ __forceinline__ void publish_barrier() {
  asm volatile("s_waitcnt lgkmcnt(0)" ::: "memory");
  __builtin_amdgcn_sched_barrier(0);
  __builtin_amdgcn_s_barrier();
}

// ---------------- fp32 -> bf16 conversion (x + 4 weight mats) ----------------
__global__ __launch_bounds__(256) void cvt_all(
    const float* __restrict__ x, const float* __restrict__ w0,
    const float* __restrict__ w1, const float* __restrict__ w2,
    const float* __restrict__ w3, u16* __restrict__ xb, u16* __restrict__ wb) {
  long i = (long)(blockIdx.x * 256 + threadIdx.x) * 8;
  const float* src; u16* dst; long off;
  if (i < 4194304) { src = x; dst = xb; off = i; }
  else {
    long k = i - 4194304; int w = (int)(k >> 20); off = k & 1048575;
    src = (w == 0) ? w0 : (w == 1) ? w1 : (w == 2) ? w2 : w3;
    dst = wb + (long)w * 1048576;
  }
  float4 a = *(const float4*)(src + off);
  float4 b = *(const float4*)(src + off + 4);
  u16x8 o;
  o[0] = f2bf(a.x); o[1] = f2bf(a.y); o[2] = f2bf(a.z); o[3] = f2bf(a.w);
  o[4] = f2bf(b.x); o[5] = f2bf(b.y); o[6] = f2bf(b.z); o[7] = f2bf(b.w);
  *(u16x8*)(dst + off) = o;
}

// ---------------- GEMM QKV: 128x128 tile, BK=64, XOR-swizzled LDS ----------
__global__ __launch_bounds__(256) void gemm_qkv(
    const u16* __restrict__ A, const u16* __restrict__ Bw,
    u16* __restrict__ Co) {
  __shared__ u16 As[128 * 64];
  __shared__ u16 Bs[128 * 64];
  const int tid = threadIdx.x, w = tid >> 6, l = tid & 63;
  const int lg = l >> 4, lr = l & 15;
  const int mb = blockIdx.x;
  const int mat = blockIdx.y >> 3, nb = blockIdx.y & 7;
  const u16* __restrict__ Bp = Bw + (long)mat * 1048576;
  const int wr = w >> 1, wc = w & 1;
  f32x4 acc[4][4] = {};
  const int srow = w * 8 + (l >> 3);
  const int scol = ((l & 7) * 8) ^ (((l >> 3) & 7) << 3);
  for (int kt = 0; kt < 16; ++kt) {
    const int kb = kt * 64;
    __syncthreads();
#pragma unroll
    for (int call = 0; call < 4; ++call) {
      int r = call * 32 + srow;
      gload_lds16(A  + (long)(mb * 128 + r) * 1024 + kb + scol, &As[call * 2048 + w * 512]);
      gload_lds16(Bp + (long)(nb * 128 + r) * 1024 + kb + scol, &Bs[call * 2048 + w * 512]);
    }
    __syncthreads();
#pragma unroll
    for (int ksub = 0; ksub < 2; ++ksub) {
      bf16x8 af[4], bf[4];
#pragma unroll
      for (int m = 0; m < 4; ++m) {
        const int row_ = wr * 64 + m * 16 + lr;
        af[m] = *(const bf16x8*)&As[row_ * 64 + ((ksub * 32 + lg * 8) ^ ((row_ & 7) << 3))];
      }
#pragma unroll
      for (int n = 0; n < 4; ++n) {
        const int row_ = wc * 64 + n * 16 + lr;
        bf[n] = *(const bf16x8*)&Bs[row_ * 64 + ((ksub * 32 + lg * 8) ^ ((row_ & 7) << 3))];
      }
#pragma unroll
      for (int m = 0; m < 4; ++m)
#pragma unroll
        for (int n = 0; n < 4; ++n)
          acc[m][n] = MFMA16(af[m], bf[n], acc[m][n]);
    }
  }
  const int row0 = mb * 128 + wr * 64, col0 = nb * 128 + wc * 64;
#pragma unroll
  for (int m = 0; m < 4; ++m)
#pragma unroll
    for (int n = 0; n < 4; ++n)
#pragma unroll
      for (int rr = 0; rr < 4; ++rr) {
        int row = row0 + m * 16 + lg * 4 + rr;
        int col = col0 + n * 16 + lr;
        float v = acc[m][n][rr];
        if (mat == 0) v *= 0.18033688011112042f;  // 0.125 * log2(e)
        Co[(long)mat * 4194304 + (long)row * 1024 + col] = f2bf(v);
      }
}

// ---------------- GEMM out-proj: 64x128 tile, BK=64 (grid 512 = 2/CU) ------
__global__ __launch_bounds__(256) void gemm_out(
    const u16* __restrict__ A, const u16* __restrict__ Bw,
    float* __restrict__ Cf, const float* __restrict__ bias) {
  __shared__ u16 As[64 * 64];
  __shared__ u16 Bs[128 * 64];
  const int tid = threadIdx.x, w = tid >> 6, l = tid & 63;
  const int lg = l >> 4, lr = l & 15;
  const int mb = blockIdx.x, nb = blockIdx.y;
  const int wr = w >> 1, wc = w & 1;
  f32x4 acc[2][4] = {};
  const int srow = w * 8 + (l >> 3);
  const int scol = ((l & 7) * 8) ^ (((l >> 3) & 7) << 3);
  for (int kt = 0; kt < 16; ++kt) {
    const int kb = kt * 64;
    __syncthreads();
#pragma unroll
    for (int call = 0; call < 2; ++call) {
      int r = call * 32 + srow;
      gload_lds16(A + (long)(mb * 64 + r) * 1024 + kb + scol, &As[call * 2048 + w * 512]);
    }
#pragma unroll
    for (int call = 0; call < 4; ++call) {
      int r = call * 32 + srow;
      gload_lds16(Bw + (long)(nb * 128 + r) * 1024 + kb + scol, &Bs[call * 2048 + w * 512]);
    }
    __syncthreads();
#pragma unroll
    for (int ksub = 0; ksub < 2; ++ksub) {
      bf16x8 af[2], bf[4];
#pragma unroll
      for (int m = 0; m < 2; ++m) {
        const int row_ = wr * 32 + m * 16 + lr;
        af[m] = *(const bf16x8*)&As[row_ * 64 + ((ksub * 32 + lg * 8) ^ ((row_ & 7) << 3))];
      }
#pragma unroll
      for (int n = 0; n < 4; ++n) {
        const int row_ = wc * 64 + n * 16 + lr;
        bf[n] = *(const bf16x8*)&Bs[row_ * 64 + ((ksub * 32 + lg * 8) ^ ((row_ & 7) << 3))];
      }
#pragma unroll
      for (int m = 0; m < 2; ++m)
#pragma unroll
        for (int n = 0; n < 4; ++n)
          acc[m][n] = MFMA16(af[m], bf[n], acc[m][n]);
    }
  }
  const int row0 = mb * 64 + wr * 32, col0 = wc * 64;
#pragma unroll
  for (int m = 0; m < 2; ++m)
#pragma unroll
    for (int n = 0; n < 4; ++n)
#pragma unroll
      for (int rr = 0; rr < 4; ++rr) {
        int row = row0 + m * 16 + lg * 4 + rr;
        int col = nb * 128 + col0 + n * 16 + lr;
        Cf[(long)row * 1024 + col] = acc[m][n][rr] + bias[col];
      }
}

// ---------------- flash attention: K-LDS + V tr-read, addr-precomputed -----
// R22: VALU audit — ~260 of 420 VALU-cy/wave-iter were recomputed addresses.
// (a) kfo[2][4]: K-frag LDS byte offsets precomputed per-lane (static idx);
//     with literal db*8192 the base folds const -> <=1 v_add per ds_read.
// (b) K/V global staging via advancing pointers (+= 65536/tile), no per-iter
//     64-bit rebuild. No sync/layout/math change -> absmax bit-identical.
__global__ __launch_bounds__(256) void attn(
    const u16* __restrict__ Qg, const u16* __restrict__ Kg,
    const u16* __restrict__ Vg, u16* __restrict__ Og) {
  __shared__ u16 Ksb[2 * 4096];   // dbuf K tile [64][64 u16], XOR-swizzled
  __shared__ u16 Vst[2 * 4160];   // dbuf V [dg][k][16] subtiled for tr-read
  const int tid = threadIdx.x, w = tid >> 6, l = tid & 63;
  const int l31 = l & 31, hi = l >> 5;

  // XCD clustering: lin%8 = XCD; 2 heads/XCD -> K+V set 2 MB < 4 MB L2/XCD.
  const int lin = blockIdx.x;
  const int xcd = lin & 7, idx = lin >> 3;
  const int head = xcd * 2 + (idx >> 5), qt = idx & 31;
  const int hb = head * 64;
  const int q0 = qt * 128 + w * 32;

  bf16x8 qf[4];
#pragma unroll
  for (int st = 0; st < 4; ++st)
    qf[st] = *(const bf16x8*)&Qg[(long)(q0 + l31) * 1024 + hb + st * 16 + hi * 8];

  f32x16 o0 = {}, o1 = {};
  f32x4 lsv = {};

  // K staging: linear gload_lds dest + pre-swizzled global source (rule 21).
  // Advancing pointers: kga/kgb start at tile 0 rows (krow, krow+32).
  const int krow = tid >> 3;
  const int ksrc = (((tid & 7) * 16) ^ ((krow & 7) << 4)) >> 1;  // u16 units
  u16* kdst = Ksb + w * 512;  // wave-uniform base; HW adds lane*16B
  const u16* kga = Kg + hb + (long)krow * 1024 + ksrc;
  const u16* kgb = kga + 32 * 1024;

#define KSTAGE(db_)                                                           \
  {                                                                           \
    gload_lds16(kga, kdst + (db_) * 4096);                                    \
    gload_lds16(kgb, kdst + (db_) * 4096 + 2048);                             \
    kga += 65536; kgb += 65536;                                               \
  }

  // K-frag LDS byte offsets, lane-constant (precomputed once).
  u32 kfo[2][4];
#pragma unroll
  for (int tt = 0; tt < 2; ++tt)
#pragma unroll
    for (int st = 0; st < 4; ++st) {
      const int row_ = tt * 32 + l31;
      const int boff_ = (st * 32 + hi * 16) ^ ((row_ & 7) << 4);
      kfo[tt][st] = (u32)(row_ * 128 + boff_);
    }

#define KFRAG(kf_, db_)                                                       \
  {                                                                           \
    _Pragma("unroll") for (int tt = 0; tt < 2; ++tt)                          \
      _Pragma("unroll") for (int st = 0; st < 4; ++st)                        \
        (kf_)[tt][st] = *(const bf16x8*)((const char*)Ksb + (db_) * 8192 +    \
                                         kfo[tt][st]);                        \
  }

#define QKT(S0_, S1_, db_)                                                    \
  {                                                                           \
    bf16x8 kf_[2][4];                                                         \
    KFRAG(kf_, db_);                                                          \
    S0_ = (f32x16){};                                                         \
    S1_ = (f32x16){};                                                         \
    __builtin_amdgcn_s_setprio(1);                                            \
    _Pragma("unroll") for (int st = 0; st < 4; ++st) {                        \
      S0_ = MFMA32(kf_[0][st], qf[st], S0_);                                  \
      S1_ = MFMA32(kf_[1][st], qf[st], S1_);                                  \
    }                                                                         \
    __builtin_amdgcn_s_setprio(0);                                            \
  }

// P pack via permlane32_swap (T12): one swap fills both frag words.
#define PACKCHUNK(SX, base_, pb_)                                             \
  {                                                                           \
    u32 a0_ = cvt_pk_bf16((SX)[(base_) + 0], (SX)[(base_) + 1]);              \
    u32 b0_ = cvt_pk_bf16((SX)[(base_) + 4], (SX)[(base_) + 5]);              \
    u32 a1_ = cvt_pk_bf16((SX)[(base_) + 2], (SX)[(base_) + 3]);              \
    u32 b1_ = cvt_pk_bf16((SX)[(base_) + 6], (SX)[(base_) + 7]);              \
    u32x2 r0_ = __builtin_amdgcn_permlane32_swap(a0_, b0_, false, false);     \
    u32x2 r1_ = __builtin_amdgcn_permlane32_swap(a1_, b1_, false, false);     \
    u32x4 fv_;                                                                \
    fv_[0] = r0_[0]; fv_[1] = r1_[0]; fv_[2] = r0_[1]; fv_[3] = r1_[1];       \
    (pb_) = __builtin_bit_cast(bf16x8, fv_);                                  \
  }

  // V staging: advancing pointers; dest lane-constant per db.
  const int vsk = (w & 1) * 32 + (l >> 1);
  const int vsd0 = (w >> 1) * 16 + (l & 1) * 8;
  const int vdbase = (w >> 1) * 1040 + (w & 1) * 512;  // u16, per-wave dest
  const u16* vga = Vg + hb + (long)vsk * 1024 + vsd0;
  const u16* vgb = vga + 32;

#define VSTAGE_TR(db_)                                                        \
  {                                                                           \
    gload_lds16(vga, Vst + (db_) * 4160 + vdbase);                            \
    gload_lds16(vgb, Vst + (db_) * 4160 + vdbase + 2080);                     \
    vga += 65536; vgb += 65536;                                               \
  }

  // tr-read per-lane base (bytes), model C: lane supplies contiguous b64 at
  // tile_base + (l&15)*8; tile_base = dg(l31>>4)*2080 + hi*256. 8B-aligned.
  const u32 vtr_base =
      (u32)(unsigned long long)(void*)Vst +
      (u32)((l31 >> 4) * 2080 + (l & 15) * 8 + hi * 256);

#define TRREAD(r_, va_, IMM)                                                  \
  asm volatile("ds_read_b64_tr_b16 %0, %1 offset:" #IMM                       \
               : "=v"(r_) : "v"(va_));

#define FINISH_TR(SC0, SC1, db_)                                              \
  {                                                                           \
    _Pragma("unroll") for (int r = 0; r < 16; ++r) {                          \
      SC0[r] = __builtin_amdgcn_exp2f(SC0[r]);                                \
      SC1[r] = __builtin_amdgcn_exp2f(SC1[r]);                                \
    }                                                                         \
    const u32 va_ = vtr_base + (u32)((db_) * 8320);                           \
    u32x2 t00, t01, t02, t03, t10, t11, t12, t13;                             \
    u32x2 t20, t21, t22, t23, t30, t31, t32, t33;                             \
    TRREAD(t00, va_, 0);    TRREAD(t01, va_, 128);                            \
    TRREAD(t02, va_, 4160); TRREAD(t03, va_, 4288);                           \
    TRREAD(t10, va_, 512);  TRREAD(t11, va_, 640);                            \
    TRREAD(t12, va_, 4672); TRREAD(t13, va_, 4800);                           \
    TRREAD(t20, va_, 1024); TRREAD(t21, va_, 1152);                           \
    TRREAD(t22, va_, 5184); TRREAD(t23, va_, 5312);                           \
    TRREAD(t30, va_, 1536); TRREAD(t31, va_, 1664);                           \
    TRREAD(t32, va_, 5696); TRREAD(t33, va_, 5824);                           \
    bf16x8 pb0, pb1, pb2, pb3;                                                \
    PACKCHUNK(SC0, 0, pb0);                                                   \
    PACKCHUNK(SC0, 8, pb1);                                                   \
    PACKCHUNK(SC1, 0, pb2);                                                   \
    PACKCHUNK(SC1, 8, pb3);                                                   \
    asm volatile("s_waitcnt lgkmcnt(0)" ::: "memory");                        \
    __builtin_amdgcn_sched_barrier(0);  /* rule #18: fence MFMA hoisting */   \
    __builtin_amdgcn_s_setprio(1);                                            \
    { u32x4 f_; f_[0]=t00[0]; f_[1]=t00[1]; f_[2]=t01[0]; f_[3]=t01[1];       \
      o0 = MFMA32(__builtin_bit_cast(bf16x8, f_), pb0, o0); }                 \
    { u32x4 f_; f_[0]=t02[0]; f_[1]=t02[1]; f_[2]=t03[0]; f_[3]=t03[1];       \
      o1 = MFMA32(__builtin_bit_cast(bf16x8, f_), pb0, o1); }                 \
    { u32x4 f_; f_[0]=t10[0]; f_[1]=t10[1]; f_[2]=t11[0]; f_[3]=t11[1];       \
      o0 = MFMA32(__builtin_bit_cast(bf16x8, f_), pb1, o0); }                 \
    { u32x4 f_; f_[0]=t12[0]; f_[1]=t12[1]; f_[2]=t13[0]; f_[3]=t13[1];       \
      o1 = MFMA32(__builtin_bit_cast(bf16x8, f_), pb1, o1); }                 \
    { u32x4 f_; f_[0]=t20[0]; f_[1]=t20[1]; f_[2]=t21[0]; f_[3]=t21[1];       \
      o0 = MFMA32(__builtin_bit_cast(bf16x8, f_), pb2, o0); }                 \
    { u32x4 f_; f_[0]=t22[0]; f_[1]=t22[1]; f_[2]=t23[0]; f_[3]=t23[1];       \
      o1 = MFMA32(__builtin_bit_cast(bf16x8, f_), pb2, o1); }                 \
    { u32x4 f_; f_[0]=t30[0]; f_[1]=t30[1]; f_[2]=t31[0]; f_[3]=t31[1];       \
      o0 = MFMA32(__builtin_bit_cast(bf16x8, f_), pb3, o0); }                 \
    { u32x4 f_; f_[0]=t32[0]; f_[1]=t32[1]; f_[2]=t33[0]; f_[3]=t33[1];       \
      o1 = MFMA32(__builtin_bit_cast(bf16x8, f_), pb3, o1); }                 \
    __builtin_amdgcn_s_setprio(0);                                            \
    _Pragma("unroll") for (int r2 = 0; r2 < 4; ++r2)                          \
      _Pragma("unroll") for (int j = 0; j < 4; ++j)                           \
        lsv[j] += SC0[r2 * 4 + j] + SC1[r2 * 4 + j];                          \
  }

  f32x16 Sa0, Sa1, Sb0, Sb1;

  // prologue: K0+V0 staged+drained; QKT(0)->Sa; K1 staged+drained
  KSTAGE(0);       // tile 0 -> kbuf 0
  VSTAGE_TR(0);    // tile 0 -> vbuf 0
  asm volatile("s_waitcnt vmcnt(0)" ::: "memory");
  publish_barrier();
  QKT(Sa0, Sa1, 0);
  KSTAGE(1);       // tile 1 -> kbuf 1
  asm volatile("s_waitcnt vmcnt(0)" ::: "memory");
  publish_barrier();

// body t: stage K(t+2)->kbuf(t&1), V(t+1)->vbuf((t+1)&1); QKT(t+1); FINISH(t)
#define BODY_TR(db_, SC0, SC1, SN0, SN1, kst_)                                \
  {                                                                           \
    if (kst_) KSTAGE(db_);                                                    \
    VSTAGE_TR((db_) ^ 1);                                                     \
    QKT(SN0, SN1, (db_) ^ 1);                                                 \
    FINISH_TR(SC0, SC1, db_);                                                 \
    asm volatile("s_waitcnt vmcnt(0)" ::: "memory");                          \
    publish_barrier();                                                        \
  }

  for (int i = 0; i < 31; ++i) {  // t = 0..61
    BODY_TR(0, Sa0, Sa1, Sb0, Sb1, true);
    BODY_TR(1, Sb0, Sb1, Sa0, Sa1, true);
  }
  BODY_TR(0, Sa0, Sa1, Sb0, Sb1, false);  // t=62: stages V63; QKT(63)
  FINISH_TR(Sb0, Sb1, 1);                 // t=63

  // epilogue: reduce ls over both k-half lanes, normalize, store ctx^T
  {
    float sls = (lsv[0] + lsv[1]) + (lsv[2] + lsv[3]);
    float s = sls + __shfl_xor(sls, 32);
    float inv = 1.0f / s;
#pragma unroll
    for (int dt = 0; dt < 2; ++dt) {
#pragma unroll
      for (int r2 = 0; r2 < 4; ++r2) {
        float v0 = dt ? o1[r2 * 4 + 0] : o0[r2 * 4 + 0];
        float v1 = dt ? o1[r2 * 4 + 1] : o0[r2 * 4 + 1];
        float v2 = dt ? o1[r2 * 4 + 2] : o0[r2 * 4 + 2];
        float v3 = dt ? o1[r2 * 4 + 3] : o0[r2 * 4 + 3];
        uint2 pk;
        pk.x = cvt_pk_bf16(v0 * inv, v1 * inv);
        pk.y = cvt_pk_bf16(v2 * inv, v3 * inv);
        const int d0 = dt * 32 + 8 * r2 + 4 * hi;
        *(uint2*)&Og[(long)(q0 + l31) * 1024 + hb + d0] = pk;
      }
    }
  }
#undef KSTAGE
#undef KFRAG
#undef QKT
#undef PACKCHUNK
#undef VSTAGE_TR
#undef TRREAD
#undef FINISH_TR
#undef BODY_TR
}

extern "C" void kernel_launch(void* const* d_in, const int* in_sizes, int n_in,
                              void* d_out, int out_size, void* d_ws, size_t ws_size,
                              hipStream_t stream) {
  const float* x  = (const float*)d_in[0];
  const float* Wq = (const float*)d_in[1];
  const float* Wk = (const float*)d_in[2];
  const float* Wv = (const float*)d_in[3];
  const float* Wo = (const float*)d_in[4];
  const float* bo = (const float*)d_in[5];
  float* out = (float*)d_out;

  u16* xb  = (u16*)d_ws;            // 4096x1024 bf16
  u16* wb  = xb + 4194304;          // 4 x 1024x1024 bf16 (Wq,Wk,Wv,Wo)
  u16* qkv = wb + 4194304;          // Q,K,V each 4096x1024 bf16
  u16* ctx = qkv + 3 * 4194304;     // 4096x1024 bf16

  cvt_all<<<dim3(4096), dim3(256), 0, stream>>>(x, Wq, Wk, Wv, Wo, xb, wb);
  gemm_qkv<<<dim3(32, 24), dim3(256), 0, stream>>>(xb, wb, qkv);
  attn<<<dim3(512), dim3(256), 0, stream>>>(qkv, qkv + 4194304, qkv + 8388608, ctx);
  gemm_out<<<dim3(64, 8), dim3(256), 0, stream>>>(ctx, wb + 3 * 1048576, out, bo);
}

// Round 23
// 153.191 us; speedup vs baseline: 1.0892x; 1.0892x over previous
//
#include <hip/hip_runtime.h>

typedef short bf16x8 __attribute__((ext_vector_type(8)));
typedef float f32x4 __attribute__((ext_vector_type(4)));
typedef float f32x16 __attribute__((ext_vector_type(16)));
typedef unsigned short u16;
typedef unsigned short u16x8 __attribute__((ext_vector_type(8)));
typedef unsigned int u32;
typedef unsigned int u32x2 __attribute__((ext_vector_type(2)));
typedef unsigned int u32x4 __attribute__((ext_vector_type(4)));

#define MFMA16(a, b, c) __builtin_amdgcn_mfma_f32_16x16x32_bf16((a), (b), (c), 0, 0, 0)
#define MFMA32(a, b, c) __builtin_amdgcn_mfma_f32_32x32x16_bf16((a), (b), (c), 0, 0, 0)

__device__ __forceinline__ u16 f2bf(float f) {
  unsigned u = __builtin_bit_cast(unsigned, f);
  return (u16)((u + 0x7fffu + ((u >> 16) & 1u)) >> 16);
}

__device__ __forceinline__ unsigned cvt_pk_bf16(float lo, float hi) {
  unsigned r;
  asm("v_cvt_pk_bf16_f32 %0, %1, %2" : "=v"(r) : "v"(lo), "v"(hi));
  return r;
}

__device__ __forceinline__ void gload_lds16(const u16* g, u16* lds) {
  __builtin_amdgcn_global_load_lds((__attribute__((address_space(1))) void*)g,
                                   (__attribute__((address_space(3))) void*)lds,
                                   16, 0, 0);
}

// Publish LDS writes + block barrier WITHOUT draining vmcnt.
__device__ __forceinline__ void publish_barrier() {
  asm volatile("s_waitcnt lgkmcnt(0)" ::: "memory");
  __builtin_amdgcn_sched_barrier(0);
  __builtin_amdgcn_s_barrier();
}

// ---------------- fp32 -> bf16 conversion (x + 4 weight mats) ----------------
__global__ __launch_bounds__(256) void cvt_all(
    const float* __restrict__ x, const float* __restrict__ w0,
    const float* __restrict__ w1, const float* __restrict__ w2,
    const float* __restrict__ w3, u16* __restrict__ xb, u16* __restrict__ wb) {
  long i = (long)(blockIdx.x * 256 + threadIdx.x) * 8;
  const float* src; u16* dst; long off;
  if (i < 4194304) { src = x; dst = xb; off = i; }
  else {
    long k = i - 4194304; int w = (int)(k >> 20); off = k & 1048575;
    src = (w == 0) ? w0 : (w == 1) ? w1 : (w == 2) ? w2 : w3;
    dst = wb + (long)w * 1048576;
  }
  float4 a = *(const float4*)(src + off);
  float4 b = *(const float4*)(src + off + 4);
  u16x8 o;
  o[0] = f2bf(a.x); o[1] = f2bf(a.y); o[2] = f2bf(a.z); o[3] = f2bf(a.w);
  o[4] = f2bf(b.x); o[5] = f2bf(b.y); o[6] = f2bf(b.z); o[7] = f2bf(b.w);
  *(u16x8*)(dst + off) = o;
}

// ---------------- GEMM  C[M,N] = A[M,K] * B[N,K]^T  (bf16 in, fp32 acc) -----
template <int MODE>
__global__ __launch_bounds__(256) void gemm_bt(
    const u16* __restrict__ A, const u16* __restrict__ Bw,
    u16* __restrict__ Co, float* __restrict__ Cf, const float* __restrict__ bias) {
  constexpr int K = 1024;
  __shared__ u16 As[128 * 32];
  __shared__ u16 Bs[128 * 32];
  const int tid = threadIdx.x, w = tid >> 6, l = tid & 63;
  const int lg = l >> 4, lr = l & 15;
  const int mb = blockIdx.x;
  int mat, nb;
  if (MODE == 0) { mat = blockIdx.y >> 3; nb = blockIdx.y & 7; }
  else           { mat = 0;               nb = blockIdx.y;     }
  const u16* __restrict__ Bp = Bw + (long)mat * 1048576;
  const int wr = w >> 1, wc = w & 1;
  f32x4 acc[4][4] = {};
  const int srow = (l >> 2), scol = (l & 3) * 8;
  for (int kt = 0; kt < K / 32; ++kt) {
    const int kb = kt * 32;
    __syncthreads();
#pragma unroll
    for (int i = 0; i < 2; ++i) {
      int r = w * 32 + i * 16 + srow;
      gload_lds16(A  + (long)(mb * 128 + r) * K + kb + scol, &As[(w * 2 + i) * 512]);
      gload_lds16(Bp + (long)(nb * 128 + r) * K + kb + scol, &Bs[(w * 2 + i) * 512]);
    }
    __syncthreads();
    bf16x8 af[4], bf[4];
#pragma unroll
    for (int m = 0; m < 4; ++m) af[m] = *(const bf16x8*)&As[(wr * 64 + m * 16 + lr) * 32 + lg * 8];
#pragma unroll
    for (int n = 0; n < 4; ++n) bf[n] = *(const bf16x8*)&Bs[(wc * 64 + n * 16 + lr) * 32 + lg * 8];
#pragma unroll
    for (int m = 0; m < 4; ++m)
#pragma unroll
      for (int n = 0; n < 4; ++n)
        acc[m][n] = MFMA16(af[m], bf[n], acc[m][n]);
  }
  const int row0 = mb * 128 + wr * 64, col0 = nb * 128 + wc * 64;
#pragma unroll
  for (int m = 0; m < 4; ++m)
#pragma unroll
    for (int n = 0; n < 4; ++n)
#pragma unroll
      for (int rr = 0; rr < 4; ++rr) {
        int row = row0 + m * 16 + lg * 4 + rr;
        int col = col0 + n * 16 + lr;
        float v = acc[m][n][rr];
        if (MODE == 0) {
          if (mat == 0) v *= 0.18033688011112042f;  // 0.125 * log2(e)
          Co[(long)mat * 4194304 + (long)row * 1024 + col] = f2bf(v);
        } else {
          Cf[(long)row * 1024 + col] = v + bias[col];
        }
      }
}

// ---------------- flash attention: K-LDS + V via ds_read_b64_tr_b16 --------
// (R20 verified: model-C tr semantics, 99.7us, absmax 1.0986e-3. R23: only
// change is __launch_bounds__(256,2) — relaxes the VGPR cap to the true
// occupancy (2 waves/SIMD, grid-capped); cannot spill or reduce residency.)
// V LDS per buf: [dg=4][k=64][16 d] u16 + 16-u16 pad/dg (dg stride 1040 u16).
__global__ __launch_bounds__(256, 2) void attn(
    const u16* __restrict__ Qg, const u16* __restrict__ Kg,
    const u16* __restrict__ Vg, u16* __restrict__ Og) {
  __shared__ u16 Ksb[2 * 4096];   // dbuf K tile [64][64 u16], XOR-swizzled
  __shared__ u16 Vst[2 * 4160];   // dbuf V [dg][k][16] subtiled for tr-read
  const int tid = threadIdx.x, w = tid >> 6, l = tid & 63;
  const int l31 = l & 31, hi = l >> 5;

  // XCD clustering: lin%8 = XCD; 2 heads/XCD -> K+V set 2 MB < 4 MB L2/XCD.
  const int lin = blockIdx.x;
  const int xcd = lin & 7, idx = lin >> 3;
  const int head = xcd * 2 + (idx >> 5), qt = idx & 31;
  const int hb = head * 64;
  const int q0 = qt * 128 + w * 32;

  const u16* __restrict__ Kh = Kg + hb;

  bf16x8 qf[4];
#pragma unroll
  for (int st = 0; st < 4; ++st)
    qf[st] = *(const bf16x8*)&Qg[(long)(q0 + l31) * 1024 + hb + st * 16 + hi * 8];

  f32x16 o0 = {}, o1 = {};
  f32x4 lsv = {};

  // K staging: linear gload_lds dest + pre-swizzled global source (rule 21)
  const int krow = tid >> 3;
  const int ksrc = (((tid & 7) * 16) ^ ((krow & 7) << 4)) >> 1;  // u16 units
  u16* kdst = Ksb + w * 512;  // wave-uniform base; HW adds lane*16B

#define KSTAGE(t_, db_)                                                       \
  {                                                                           \
    gload_lds16(Kh + (long)((t_) * 64 + krow) * 1024 + ksrc,                  \
                kdst + (db_) * 4096);                                         \
    gload_lds16(Kh + (long)((t_) * 64 + 32 + krow) * 1024 + ksrc,             \
                kdst + (db_) * 4096 + 2048);                                  \
  }

#define KFRAG(kf_, db_)                                                       \
  {                                                                           \
    _Pragma("unroll") for (int tt = 0; tt < 2; ++tt)                          \
      _Pragma("unroll") for (int st = 0; st < 4; ++st) {                      \
        const int row_ = tt * 32 + l31;                                       \
        const int boff_ = (st * 32 + hi * 16) ^ ((row_ & 7) << 4);            \
        (kf_)[tt][st] =                                                       \
            *(const bf16x8*)&Ksb[(db_) * 4096 + row_ * 64 + (boff_ >> 1)];    \
      }                                                                       \
  }

#define QKT(S0_, S1_, db_)                                                    \
  {                                                                           \
    bf16x8 kf_[2][4];                                                         \
    KFRAG(kf_, db_);                                                          \
    S0_ = (f32x16){};                                                         \
    S1_ = (f32x16){};                                                         \
    __builtin_amdgcn_s_setprio(1);                                            \
    _Pragma("unroll") for (int st = 0; st < 4; ++st) {                        \
      S0_ = MFMA32(kf_[0][st], qf[st], S0_);                                  \
      S1_ = MFMA32(kf_[1][st], qf[st], S1_);                                  \
    }                                                                         \
    __builtin_amdgcn_s_setprio(0);                                            \
  }

// P pack via permlane32_swap (T12): one swap fills both frag words.
#define PACKCHUNK(SX, base_, pb_)                                             \
  {                                                                           \
    u32 a0_ = cvt_pk_bf16((SX)[(base_) + 0], (SX)[(base_) + 1]);              \
    u32 b0_ = cvt_pk_bf16((SX)[(base_) + 4], (SX)[(base_) + 5]);              \
    u32 a1_ = cvt_pk_bf16((SX)[(base_) + 2], (SX)[(base_) + 3]);              \
    u32 b1_ = cvt_pk_bf16((SX)[(base_) + 6], (SX)[(base_) + 7]);              \
    u32x2 r0_ = __builtin_amdgcn_permlane32_swap(a0_, b0_, false, false);     \
    u32x2 r1_ = __builtin_amdgcn_permlane32_swap(a1_, b1_, false, false);     \
    u32x4 fv_;                                                                \
    fv_[0] = r0_[0]; fv_[1] = r1_[0]; fv_[2] = r0_[1]; fv_[3] = r1_[1];       \
    (pb_) = __builtin_bit_cast(bf16x8, fv_);                                  \
  }

  // V staging geometry: call A covers dg = w>>1, call B dg = 2+(w>>1);
  // within call: k = (w&1)*32 + (l>>1), d-half = l&1.
  const int vsk = (w & 1) * 32 + (l >> 1);
  const int vsd0 = (w >> 1) * 16 + (l & 1) * 8;
  const int vdbase = (w >> 1) * 1040 + (w & 1) * 512;  // u16, per-wave dest

#define VSTAGE_TR(t_, db_)                                                    \
  {                                                                           \
    gload_lds16(Vg + (long)((t_) * 64 + vsk) * 1024 + hb + vsd0,              \
                Vst + (db_) * 4160 + vdbase);                                 \
    gload_lds16(Vg + (long)((t_) * 64 + vsk) * 1024 + hb + vsd0 + 32,         \
                Vst + (db_) * 4160 + vdbase + 2080);                          \
  }

  // tr-read per-lane base (bytes), model C: lane supplies contiguous b64 at
  // tile_base + (l&15)*8; tile_base = dg(l31>>4)*2080 + hi*256. 8B-aligned.
  const u32 vtr_base =
      (u32)(unsigned long long)(void*)Vst +
      (u32)((l31 >> 4) * 2080 + (l & 15) * 8 + hi * 256);

#define TRREAD(r_, va_, IMM)                                                  \
  asm volatile("ds_read_b64_tr_b16 %0, %1 offset:" #IMM                       \
               : "=v"(r_) : "v"(va_));

#define FINISH_TR(SC0, SC1, db_)                                              \
  {                                                                           \
    _Pragma("unroll") for (int r = 0; r < 16; ++r) {                          \
      SC0[r] = __builtin_amdgcn_exp2f(SC0[r]);                                \
      SC1[r] = __builtin_amdgcn_exp2f(SC1[r]);                                \
    }                                                                         \
    const u32 va_ = vtr_base + (u32)((db_) * 8320);                           \
    u32x2 t00, t01, t02, t03, t10, t11, t12, t13;                             \
    u32x2 t20, t21, t22, t23, t30, t31, t32, t33;                             \
    TRREAD(t00, va_, 0);    TRREAD(t01, va_, 128);                            \
    TRREAD(t02, va_, 4160); TRREAD(t03, va_, 4288);                           \
    TRREAD(t10, va_, 512);  TRREAD(t11, va_, 640);                            \
    TRREAD(t12, va_, 4672); TRREAD(t13, va_, 4800);                           \
    TRREAD(t20, va_, 1024); TRREAD(t21, va_, 1152);                           \
    TRREAD(t22, va_, 5184); TRREAD(t23, va_, 5312);                           \
    TRREAD(t30, va_, 1536); TRREAD(t31, va_, 1664);                           \
    TRREAD(t32, va_, 5696); TRREAD(t33, va_, 5824);                           \
    bf16x8 pb0, pb1, pb2, pb3;                                                \
    PACKCHUNK(SC0, 0, pb0);                                                   \
    PACKCHUNK(SC0, 8, pb1);                                                   \
    PACKCHUNK(SC1, 0, pb2);                                                   \
    PACKCHUNK(SC1, 8, pb3);                                                   \
    asm volatile("s_waitcnt lgkmcnt(0)" ::: "memory");                        \
    __builtin_amdgcn_sched_barrier(0);  /* rule #18: fence MFMA hoisting */   \
    __builtin_amdgcn_s_setprio(1);                                            \
    { u32x4 f_; f_[0]=t00[0]; f_[1]=t00[1]; f_[2]=t01[0]; f_[3]=t01[1];       \
      o0 = MFMA32(__builtin_bit_cast(bf16x8, f_), pb0, o0); }                 \
    { u32x4 f_; f_[0]=t02[0]; f_[1]=t02[1]; f_[2]=t03[0]; f_[3]=t03[1];       \
      o1 = MFMA32(__builtin_bit_cast(bf16x8, f_), pb0, o1); }                 \
    { u32x4 f_; f_[0]=t10[0]; f_[1]=t10[1]; f_[2]=t11[0]; f_[3]=t11[1];       \
      o0 = MFMA32(__builtin_bit_cast(bf16x8, f_), pb1, o0); }                 \
    { u32x4 f_; f_[0]=t12[0]; f_[1]=t12[1]; f_[2]=t13[0]; f_[3]=t13[1];       \
      o1 = MFMA32(__builtin_bit_cast(bf16x8, f_), pb1, o1); }                 \
    { u32x4 f_; f_[0]=t20[0]; f_[1]=t20[1]; f_[2]=t21[0]; f_[3]=t21[1];       \
      o0 = MFMA32(__builtin_bit_cast(bf16x8, f_), pb2, o0); }                 \
    { u32x4 f_; f_[0]=t22[0]; f_[1]=t22[1]; f_[2]=t23[0]; f_[3]=t23[1];       \
      o1 = MFMA32(__builtin_bit_cast(bf16x8, f_), pb2, o1); }                 \
    { u32x4 f_; f_[0]=t30[0]; f_[1]=t30[1]; f_[2]=t31[0]; f_[3]=t31[1];       \
      o0 = MFMA32(__builtin_bit_cast(bf16x8, f_), pb3, o0); }                 \
    { u32x4 f_; f_[0]=t32[0]; f_[1]=t32[1]; f_[2]=t33[0]; f_[3]=t33[1];       \
      o1 = MFMA32(__builtin_bit_cast(bf16x8, f_), pb3, o1); }                 \
    __builtin_amdgcn_s_setprio(0);                                            \
    _Pragma("unroll") for (int r2 = 0; r2 < 4; ++r2)                          \
      _Pragma("unroll") for (int j = 0; j < 4; ++j)                           \
        lsv[j] += SC0[r2 * 4 + j] + SC1[r2 * 4 + j];                          \
  }

  f32x16 Sa0, Sa1, Sb0, Sb1;

  // prologue: K0+V0 staged+drained; QKT(0)->Sa; K1 staged+drained
  KSTAGE(0, 0);
  VSTAGE_TR(0, 0);
  asm volatile("s_waitcnt vmcnt(0)" ::: "memory");
  publish_barrier();
  QKT(Sa0, Sa1, 0);
  KSTAGE(1, 1);
  asm volatile("s_waitcnt vmcnt(0)" ::: "memory");
  publish_barrier();

// body t: stage K(t+2)->kbuf(t&1), V(t+1)->vbuf((t+1)&1); QKT(t+1); FINISH(t)
#define BODY_TR(t_, db_, SC0, SC1, SN0, SN1, kst_)                            \
  {                                                                           \
    if (kst_) KSTAGE((t_) + 2, db_);                                          \
    VSTAGE_TR((t_) + 1, (db_) ^ 1);                                           \
    QKT(SN0, SN1, (db_) ^ 1);                                                 \
    FINISH_TR(SC0, SC1, db_);                                                 \
    asm volatile("s_waitcnt vmcnt(0)" ::: "memory");                          \
    publish_barrier();                                                        \
  }

  for (int i = 0; i < 31; ++i) {  // t = 0..61
    BODY_TR(2 * i, 0, Sa0, Sa1, Sb0, Sb1, true);
    BODY_TR(2 * i + 1, 1, Sb0, Sb1, Sa0, Sa1, true);
  }
  BODY_TR(62, 0, Sa0, Sa1, Sb0, Sb1, false);  // stages V63; QKT(63)
  FINISH_TR(Sb0, Sb1, 1);                     // t = 63

  // epilogue: reduce ls over both k-half lanes, normalize, store ctx^T
  {
    float sls = (lsv[0] + lsv[1]) + (lsv[2] + lsv[3]);
    float s = sls + __shfl_xor(sls, 32);
    float inv = 1.0f / s;
#pragma unroll
    for (int dt = 0; dt < 2; ++dt) {
#pragma unroll
      for (int r2 = 0; r2 < 4; ++r2) {
        float v0 = dt ? o1[r2 * 4 + 0] : o0[r2 * 4 + 0];
        float v1 = dt ? o1[r2 * 4 + 1] : o0[r2 * 4 + 1];
        float v2 = dt ? o1[r2 * 4 + 2] : o0[r2 * 4 + 2];
        float v3 = dt ? o1[r2 * 4 + 3] : o0[r2 * 4 + 3];
        uint2 pk;
        pk.x = cvt_pk_bf16(v0 * inv, v1 * inv);
        pk.y = cvt_pk_bf16(v2 * inv, v3 * inv);
        const int d0 = dt * 32 + 8 * r2 + 4 * hi;
        *(uint2*)&Og[(long)(q0 + l31) * 1024 + hb + d0] = pk;
      }
    }
  }
#undef KSTAGE
#undef KFRAG
#undef QKT
#undef PACKCHUNK
#undef VSTAGE_TR
#undef TRREAD
#undef FINISH_TR
#undef BODY_TR
}

extern "C" void kernel_launch(void* const* d_in, const int* in_sizes, int n_in,
                              void* d_out, int out_size, void* d_ws, size_t ws_size,
                              hipStream_t stream) {
  const float* x  = (const float*)d_in[0];
  const float* Wq = (const float*)d_in[1];
  const float* Wk = (const float*)d_in[2];
  const float* Wv = (const float*)d_in[3];
  const float* Wo = (const float*)d_in[4];
  const float* bo = (const float*)d_in[5];
  float* out = (float*)d_out;

  u16* xb  = (u16*)d_ws;            // 4096x1024 bf16
  u16* wb  = xb + 4194304;          // 4 x 1024x1024 bf16 (Wq,Wk,Wv,Wo)
  u16* qkv = wb + 4194304;          // Q,K,V each 4096x1024 bf16
  u16* ctx = qkv + 3 * 4194304;     // 4096x1024 bf16

  cvt_all<<<dim3(4096), dim3(256), 0, stream>>>(x, Wq, Wk, Wv, Wo, xb, wb);
  gemm_bt<0><<<dim3(32, 24), dim3(256), 0, stream>>>(xb, wb, qkv, nullptr, nullptr);
  attn<<<dim3(512), dim3(256), 0, stream>>>(qkv, qkv + 4194304, qkv + 8388608, ctx);
  gemm_bt<1><<<dim3(32, 8), dim3(256), 0, stream>>>(ctx, wb + 3 * 1048576, nullptr, out, bo);
}